// Round 3
// baseline (963.358 us; speedup 1.0000x reference)
//
#include <hip/hip_runtime.h>
#include <math.h>

// RWKV-6 fused recurrent WKV, chunked linear scan, j-split waves.
// B=4, T=2048, H=16, N=64, fp32.
//
// Per (b,h):  S[i][j] <- d_t[i]*S[i][j] + k_t[i]*v_t[j]
//             o_t[j]  = sum_i r_i*S_ij  +  v_j * sruk,  sruk = sum_i r_i*u_i*k_i
//
// K1: per chunk, recurrence from zero -> L_g[i][j], A_g[i]=prod d; also sruk[t]
// K2: per (b,h,i,j): S0_{g+1} = A_g[i]*S0_g + L_g  (in place, L -> S0)
// K3: per chunk, recurrence from S0_g -> outputs
//
// Wave decomposition (K1/K3): one wave per (bh, g, jq). Lane l owns column
// j = 16*jq + (l&15) and i-rows [16*(l>>4), +16) -> S[16] per lane (~45 VGPR,
// 8 waves/SIMD). Output sum over i closes with shfl_xor(16),(32). Single-wave
// blocks: LDS pipe is in-order within a wave -> no barriers, no double buffer.
// LDS broadcast arrays padded [4][17] so the 4 iq-group addresses hit disjoint
// banks (group q, slot n -> banks 4n+4q..+3 for float4; 2n+2q,+1 for float2).

namespace {
constexpr int B = 4, T = 2048, H = 16, N = 64;
constexpr int BH = B * H;
constexpr int NG = 32;           // chunks per (b,h)
constexpr int TC = T / NG;       // 64 steps per chunk

__device__ __forceinline__ float decay_of(float w) {
    return expf(-expf(w));       // RWKV-6: d = exp(-exp(w)) in (0,1)
}

__device__ __forceinline__ float wave_sum64(float x) {
#pragma unroll
    for (int m = 1; m < 64; m <<= 1) x += __shfl_xor(x, m, 64);
    return x;
}

// ---------------- K1: chunk-local recurrence from zero state ----------------
template<int STEPS, int NGT>
__global__ __launch_bounds__(64, 8)
void k1_chunk_local(const float* __restrict__ rp, const float* __restrict__ kp,
                    const float* __restrict__ vp, const float* __restrict__ wp,
                    const float* __restrict__ up,
                    float* __restrict__ L, float* __restrict__ A,
                    float* __restrict__ SR)
{
    const int blk = blockIdx.x;               // (bh, g, jq)
    const int jq  = blk & 3;
    const int g   = (blk >> 2) & (NGT - 1);
    const int bh  = blk / (4 * NGT);
    const int b   = bh / H;
    const int h   = bh - b * H;
    const int l   = threadIdx.x;
    const int n16 = l & 15;
    const int iq  = l >> 4;
    const int j   = jq * 16 + n16;

    __shared__ float2 kd[4 * 17];             // padded: slot(i) = (i>>4)*17+(i&15)

    float S[16];
#pragma unroll
    for (int n = 0; n < 16; ++n) S[n] = 0.f;

    float ad = 1.f;                           // running decay product for i == l
    const int stride = H * N;
    int base = ((b * T + g * STEPS) * H + h) * N;
    const float ul = up[h * N + l];

    float kl = kp[base + l], wl = wp[base + l], vj = vp[base + j];
    float rl = (jq == 0) ? rp[base + l] : 0.f;
    for (int tt = 0; tt < STEPS; ++tt) {
        const int nb = (tt + 1 < STEPS) ? base + stride : base;   // clamped prefetch
        const float kn = kp[nb + l], wn = wp[nb + l], vn = vp[nb + j];
        const float rn = (jq == 0) ? rp[nb + l] : 0.f;

        const float dl = decay_of(wl);
        ad *= dl;
        if (jq == 0) {                        // wave-uniform branch
            const float sruk = wave_sum64(rl * ul * kl);
            if (l == 0) SR[bh * T + g * STEPS + tt] = sruk;
        }
        kd[iq * 17 + n16] = make_float2(kl, dl);
#pragma unroll
        for (int n = 0; n < 16; ++n) {
            const float2 x = kd[iq * 17 + n];              // broadcast ds_read_b64
            S[n] = fmaf(x.y, S[n], x.x * vj);
        }
        base = nb; kl = kn; wl = wn; vj = vn; rl = rn;
    }

    const int cbase = (bh * NGT + g) * (N * N);
#pragma unroll
    for (int n = 0; n < 16; ++n) L[cbase + (iq * 16 + n) * N + j] = S[n];
    if (jq == 0) A[(bh * NGT + g) * N + l] = ad;
}

// ---------------- K2: inter-chunk scan, in place (L -> S0), float4 ----------
__global__ __launch_bounds__(256)
void k2_scan(float* __restrict__ L, const float* __restrict__ A, int NGr)
{
    const int tid = blockIdx.x * 256 + threadIdx.x;   // over BH*N*N/4
    const int j4 = tid & (N / 4 - 1);
    const int i  = (tid >> 4) & (N - 1);
    const int bh = tid >> 10;

    float4* L4 = (float4*)L;
    const int lstride = N * N / 4;
    int lidx = bh * NGr * lstride + i * (N / 4) + j4;
    int aidx = bh * NGr * N + i;

    float4 S = make_float4(0.f, 0.f, 0.f, 0.f);
    for (int g = 0; g < NGr; ++g) {
        const float4 l = L4[lidx];
        const float  a = A[aidx];
        L4[lidx] = S;                // state at START of chunk g
        S.x = fmaf(a, S.x, l.x);
        S.y = fmaf(a, S.y, l.y);
        S.z = fmaf(a, S.z, l.z);
        S.w = fmaf(a, S.w, l.w);
        lidx += lstride;
        aidx += N;
    }
}

// ---------------- K3: chunk recurrence with true init state -> outputs ------
// SEQ=true is the no-workspace fallback (S0/SR null, zero init, in-wave sruk).
template<int STEPS, int NGT, bool SEQ>
__global__ __launch_bounds__(64, 8)
void k3_chunk_out(const float* __restrict__ rp, const float* __restrict__ kp,
                  const float* __restrict__ vp, const float* __restrict__ wp,
                  const float* __restrict__ up,
                  const float* __restrict__ S0, const float* __restrict__ SR,
                  float* __restrict__ out)
{
    const int blk = blockIdx.x;               // (bh, g, jq)
    const int jq  = blk & 3;
    const int g   = (blk >> 2) & (NGT - 1);
    const int bh  = blk / (4 * NGT);
    const int b   = bh / H;
    const int h   = bh - b * H;
    const int l   = threadIdx.x;
    const int n16 = l & 15;
    const int iq  = l >> 4;
    const int j   = jq * 16 + n16;

    __shared__ float4 rkd[4 * 17];            // padded broadcast: {r_i,k_i,d_i,-}

    const int cbase = (bh * NGT + g) * (N * N);
    float S[16];
    if (!SEQ) {
#pragma unroll
        for (int n = 0; n < 16; ++n) S[n] = S0[cbase + (iq * 16 + n) * N + j];
    } else {
#pragma unroll
        for (int n = 0; n < 16; ++n) S[n] = 0.f;
    }

    const float ul = SEQ ? up[h * N + l] : 0.f;
    const int stride = H * N;
    int base = ((b * T + g * STEPS) * H + h) * N;

    float rl = rp[base + l], kl = kp[base + l], wl = wp[base + l], vj = vp[base + j];
    for (int tt = 0; tt < STEPS; ++tt) {
        const int nb = (tt + 1 < STEPS) ? base + stride : base;   // clamped prefetch
        const float rn = rp[nb + l], kn = kp[nb + l], wn = wp[nb + l], vn = vp[nb + j];

        const float dl = decay_of(wl);
        float sr;
        if (SEQ) sr = wave_sum64(rl * ul * kl);
        else     sr = SR[bh * T + g * STEPS + tt];   // uniform scalar, L2-hot

        rkd[iq * 17 + n16] = make_float4(rl, kl, dl, 0.f);

        float o0 = 0.f, o1 = 0.f;
#pragma unroll
        for (int n = 0; n < 16; n += 2) {
            const float4 x0 = rkd[iq * 17 + n];            // broadcast ds_read_b128
            const float4 x1 = rkd[iq * 17 + n + 1];
            o0 = fmaf(x0.x, S[n],     o0);
            S[n]     = fmaf(x0.z, S[n],     x0.y * vj);
            o1 = fmaf(x1.x, S[n + 1], o1);
            S[n + 1] = fmaf(x1.z, S[n + 1], x1.y * vj);
        }
        float o = o0 + o1;
        o += __shfl_xor(o, 16, 64);
        o += __shfl_xor(o, 32, 64);           // now o = sum over ALL i, all lanes
        if (iq == 0) out[base + j] = fmaf(sr, vj, o);

        base = nb; rl = rn; kl = kn; wl = wn; vj = vn;
    }
}

} // anon namespace

extern "C" void kernel_launch(void* const* d_in, const int* in_sizes, int n_in,
                              void* d_out, int out_size, void* d_ws, size_t ws_size,
                              hipStream_t stream)
{
    const float* r = (const float*)d_in[0];
    const float* k = (const float*)d_in[1];
    const float* v = (const float*)d_in[2];
    const float* w = (const float*)d_in[3];
    const float* u = (const float*)d_in[4];
    float* out = (float*)d_out;

    const size_t l_elems  = (size_t)BH * NG * N * N;   // 8,388,608
    const size_t a_elems  = (size_t)BH * NG * N;       // 131,072
    const size_t sr_elems = (size_t)BH * T;            // 131,072
    const size_t ws_need  = (l_elems + a_elems + sr_elems) * sizeof(float); // ~33 MiB

    if (ws_size >= ws_need) {
        float* L  = (float*)d_ws;
        float* A  = L + l_elems;
        float* SR = A + a_elems;
        k1_chunk_local<TC, NG><<<BH * NG * 4, 64, 0, stream>>>(r, k, v, w, u, L, A, SR);
        k2_scan<<<(BH * N * N / 4) / 256, 256, 0, stream>>>(L, A, NG);
        k3_chunk_out<TC, NG, false><<<BH * NG * 4, 64, 0, stream>>>(r, k, v, w, u, L, SR, out);
    } else {
        // No-workspace fallback: sequential over T per (bh, jq). Slow but correct.
        k3_chunk_out<T, 1, true><<<BH * 4, 64, 0, stream>>>(r, k, v, w, u,
                                                            nullptr, nullptr, out);
    }
}

// Round 4
// 297.506 us; speedup vs baseline: 3.2381x; 3.2381x over previous
//
#include <hip/hip_runtime.h>
#include <math.h>

// RWKV-6 fused recurrent WKV, chunked linear scan, j-split waves.
// B=4, T=2048, H=16, N=64, fp32.
//
// Per (b,h):  S[i][j] <- d_t[i]*S[i][j] + k_t[i]*v_t[j]
//             o_t[j]  = sum_i r_i*S_ij  +  v_j * sruk,  sruk = sum_i r_i*u_i*k_i
//
// K1: per chunk, recurrence from zero -> L_g[i][j], A_g[i]=prod d; also sruk[t]
// K2: per (b,h,i,j): S0_{g+1} = A_g[i]*S0_g + L_g  (in place, L -> S0)
// K3: per chunk, recurrence from S0_g -> outputs
//
// Wave decomposition (K1/K3): one wave per (bh, g, jq). Lane l owns column
// j = 16*jq + (l&15) and i-rows [16*(l>>4), +16) -> S[16] per lane.
// Output sum over i closes with shfl_xor(16),(32). Single-wave blocks: LDS
// pipe is in-order within a wave -> no barriers, no double buffer.
// LDS broadcast arrays padded [4][17] so the 4 iq-group addresses hit
// disjoint banks.
//
// REGISTER DISCIPLINE (round-3 lesson): __launch_bounds__(64,8) caps the
// unified VGPR/AGPR budget at 64 -> the compiler spilled S[16] to scratch
// (WRITE_SIZE 36MB -> 2.6GB, 6x regression). (64,4) gives a 128-reg budget:
// S[16]+overhead (~60 VGPR) fits with no spill and no AGPR round-trips.

namespace {
constexpr int B = 4, T = 2048, H = 16, N = 64;
constexpr int BH = B * H;
constexpr int NG = 32;           // chunks per (b,h)
constexpr int TC = T / NG;       // 64 steps per chunk

__device__ __forceinline__ float decay_of(float w) {
    return expf(-expf(w));       // RWKV-6: d = exp(-exp(w)) in (0,1)
}

__device__ __forceinline__ float wave_sum64(float x) {
#pragma unroll
    for (int m = 1; m < 64; m <<= 1) x += __shfl_xor(x, m, 64);
    return x;
}

// ---------------- K1: chunk-local recurrence from zero state ----------------
template<int STEPS, int NGT>
__global__ __launch_bounds__(64, 4)
void k1_chunk_local(const float* __restrict__ rp, const float* __restrict__ kp,
                    const float* __restrict__ vp, const float* __restrict__ wp,
                    const float* __restrict__ up,
                    float* __restrict__ L, float* __restrict__ A,
                    float* __restrict__ SR)
{
    const int blk = blockIdx.x;               // (bh, g, jq)
    const int jq  = blk & 3;
    const int g   = (blk >> 2) & (NGT - 1);
    const int bh  = blk / (4 * NGT);
    const int b   = bh / H;
    const int h   = bh - b * H;
    const int l   = threadIdx.x;
    const int n16 = l & 15;
    const int iq  = l >> 4;
    const int j   = jq * 16 + n16;

    __shared__ float2 kd[4 * 17];             // padded: slot(i) = (i>>4)*17+(i&15)

    float S[16];
#pragma unroll
    for (int n = 0; n < 16; ++n) S[n] = 0.f;

    float ad = 1.f;                           // running decay product for i == l
    const int stride = H * N;
    int base = ((b * T + g * STEPS) * H + h) * N;
    const float ul = up[h * N + l];

    float kl = kp[base + l], wl = wp[base + l], vj = vp[base + j];
    float rl = (jq == 0) ? rp[base + l] : 0.f;
    for (int tt = 0; tt < STEPS; ++tt) {
        const int nb = (tt + 1 < STEPS) ? base + stride : base;   // clamped prefetch
        const float kn = kp[nb + l], wn = wp[nb + l], vn = vp[nb + j];
        const float rn = (jq == 0) ? rp[nb + l] : 0.f;

        const float dl = decay_of(wl);
        ad *= dl;
        if (jq == 0) {                        // wave-uniform branch
            const float sruk = wave_sum64(rl * ul * kl);
            if (l == 0) SR[bh * T + g * STEPS + tt] = sruk;
        }
        kd[iq * 17 + n16] = make_float2(kl, dl);
#pragma unroll
        for (int n = 0; n < 16; ++n) {
            const float2 x = kd[iq * 17 + n];              // broadcast ds_read_b64
            S[n] = fmaf(x.y, S[n], x.x * vj);
        }
        base = nb; kl = kn; wl = wn; vj = vn; rl = rn;
    }

    const int cbase = (bh * NGT + g) * (N * N);
#pragma unroll
    for (int n = 0; n < 16; ++n) L[cbase + (iq * 16 + n) * N + j] = S[n];
    if (jq == 0) A[(bh * NGT + g) * N + l] = ad;
}

// ---------------- K2: inter-chunk scan, in place (L -> S0), float4 ----------
__global__ __launch_bounds__(256)
void k2_scan(float* __restrict__ L, const float* __restrict__ A, int NGr)
{
    const int tid = blockIdx.x * 256 + threadIdx.x;   // over BH*N*N/4
    const int j4 = tid & (N / 4 - 1);
    const int i  = (tid >> 4) & (N - 1);
    const int bh = tid >> 10;

    float4* L4 = (float4*)L;
    const int lstride = N * N / 4;
    int lidx = bh * NGr * lstride + i * (N / 4) + j4;
    int aidx = bh * NGr * N + i;

    float4 S = make_float4(0.f, 0.f, 0.f, 0.f);
    for (int g = 0; g < NGr; ++g) {
        const float4 l = L4[lidx];
        const float  a = A[aidx];
        L4[lidx] = S;                // state at START of chunk g
        S.x = fmaf(a, S.x, l.x);
        S.y = fmaf(a, S.y, l.y);
        S.z = fmaf(a, S.z, l.z);
        S.w = fmaf(a, S.w, l.w);
        lidx += lstride;
        aidx += N;
    }
}

// ---------------- K3: chunk recurrence with true init state -> outputs ------
// SEQ=true is the no-workspace fallback (S0/SR null, zero init, in-wave sruk).
template<int STEPS, int NGT, bool SEQ>
__global__ __launch_bounds__(64, 4)
void k3_chunk_out(const float* __restrict__ rp, const float* __restrict__ kp,
                  const float* __restrict__ vp, const float* __restrict__ wp,
                  const float* __restrict__ up,
                  const float* __restrict__ S0, const float* __restrict__ SR,
                  float* __restrict__ out)
{
    const int blk = blockIdx.x;               // (bh, g, jq)
    const int jq  = blk & 3;
    const int g   = (blk >> 2) & (NGT - 1);
    const int bh  = blk / (4 * NGT);
    const int b   = bh / H;
    const int h   = bh - b * H;
    const int l   = threadIdx.x;
    const int n16 = l & 15;
    const int iq  = l >> 4;
    const int j   = jq * 16 + n16;

    __shared__ float4 rkd[4 * 17];            // padded broadcast: {r_i,k_i,d_i,-}

    const int cbase = (bh * NGT + g) * (N * N);
    float S[16];
    if (!SEQ) {
#pragma unroll
        for (int n = 0; n < 16; ++n) S[n] = S0[cbase + (iq * 16 + n) * N + j];
    } else {
#pragma unroll
        for (int n = 0; n < 16; ++n) S[n] = 0.f;
    }

    const float ul = SEQ ? up[h * N + l] : 0.f;
    const int stride = H * N;
    int base = ((b * T + g * STEPS) * H + h) * N;

    float rl = rp[base + l], kl = kp[base + l], wl = wp[base + l], vj = vp[base + j];
    for (int tt = 0; tt < STEPS; ++tt) {
        const int nb = (tt + 1 < STEPS) ? base + stride : base;   // clamped prefetch
        const float rn = rp[nb + l], kn = kp[nb + l], wn = wp[nb + l], vn = vp[nb + j];

        const float dl = decay_of(wl);
        float sr;
        if (SEQ) sr = wave_sum64(rl * ul * kl);
        else     sr = SR[bh * T + g * STEPS + tt];   // uniform scalar, L2-hot

        rkd[iq * 17 + n16] = make_float4(rl, kl, dl, 0.f);

        float o0 = 0.f, o1 = 0.f;
#pragma unroll
        for (int n = 0; n < 16; n += 2) {
            const float4 x0 = rkd[iq * 17 + n];            // broadcast ds_read_b128
            const float4 x1 = rkd[iq * 17 + n + 1];
            o0 = fmaf(x0.x, S[n],     o0);
            S[n]     = fmaf(x0.z, S[n],     x0.y * vj);
            o1 = fmaf(x1.x, S[n + 1], o1);
            S[n + 1] = fmaf(x1.z, S[n + 1], x1.y * vj);
        }
        float o = o0 + o1;
        o += __shfl_xor(o, 16, 64);
        o += __shfl_xor(o, 32, 64);           // now o = sum over ALL i, all lanes
        if (iq == 0) out[base + j] = fmaf(sr, vj, o);

        base = nb; rl = rn; kl = kn; wl = wn; vj = vn;
    }
}

} // anon namespace

extern "C" void kernel_launch(void* const* d_in, const int* in_sizes, int n_in,
                              void* d_out, int out_size, void* d_ws, size_t ws_size,
                              hipStream_t stream)
{
    const float* r = (const float*)d_in[0];
    const float* k = (const float*)d_in[1];
    const float* v = (const float*)d_in[2];
    const float* w = (const float*)d_in[3];
    const float* u = (const float*)d_in[4];
    float* out = (float*)d_out;

    const size_t l_elems  = (size_t)BH * NG * N * N;   // 8,388,608
    const size_t a_elems  = (size_t)BH * NG * N;       // 131,072
    const size_t sr_elems = (size_t)BH * T;            // 131,072
    const size_t ws_need  = (l_elems + a_elems + sr_elems) * sizeof(float); // ~33 MiB

    if (ws_size >= ws_need) {
        float* L  = (float*)d_ws;
        float* A  = L + l_elems;
        float* SR = A + a_elems;
        k1_chunk_local<TC, NG><<<BH * NG * 4, 64, 0, stream>>>(r, k, v, w, u, L, A, SR);
        k2_scan<<<(BH * N * N / 4) / 256, 256, 0, stream>>>(L, A, NG);
        k3_chunk_out<TC, NG, false><<<BH * NG * 4, 64, 0, stream>>>(r, k, v, w, u, L, SR, out);
    } else {
        // No-workspace fallback: sequential over T per (bh, jq). Slow but correct.
        k3_chunk_out<T, 1, true><<<BH * 4, 64, 0, stream>>>(r, k, v, w, u,
                                                            nullptr, nullptr, out);
    }
}